// Round 1
// baseline (1037.016 us; speedup 1.0000x reference)
//
#include <hip/hip_runtime.h>
#include <hip/hip_bf16.h>
#include <math.h>

// Problem dims (fixed by reference setup)
#define BATCH   2
#define LSEQ    1024
#define BLTOT   2048          // B*L
#define DMODEL  512
#define NHEAD   8
#define DHEAD   64
#define PDIM    1824          // 512*3 + 96*3
#define AUGW    80            // 78 used, padded to 80
#define ODIM    608           // 512 + 96

// ---------------------------------------------------------------------------
// Generic tiled f32 GEMM.
//   C[i,n] = sum_k A[i,k] * B'[k,n]
//   BT=false: B is row-major [K][ldb]   (B'[k,n] = B[k*ldb+n])
//   BT=true : B is row-major [N][ldb]   (B'[k,n] = B[n*ldb+k])  i.e. C = A*B^T
// blockIdx.z batches (A += z*strideA etc).
// Tile 64x64, BK=16, 256 threads, 4x4 micro-tile per thread.
// ---------------------------------------------------------------------------
template <bool BT>
__global__ __launch_bounds__(256)
void gemm_f32_kernel(const float* __restrict__ A, const float* __restrict__ B,
                     float* __restrict__ C, int M, int N, int K,
                     int lda, int ldb, int ldc,
                     long long strideA, long long strideB, long long strideC)
{
    A += (long long)blockIdx.z * strideA;
    B += (long long)blockIdx.z * strideB;
    C += (long long)blockIdx.z * strideC;

    __shared__ float As[16][64 + 1];
    __shared__ float Bs[16][64 + 1];

    const int tid = threadIdx.x;
    const int tx = tid & 15;        // 0..15  (n direction)
    const int ty = tid >> 4;        // 0..15  (m direction)
    const int row0 = blockIdx.y * 64;
    const int col0 = blockIdx.x * 64;

    float acc[4][4] = {};

    for (int k0 = 0; k0 < K; k0 += 16) {
        // load A tile: 64 rows x 16 k
        {
            const int m = tid >> 4;     // 0..15
            const int k = tid & 15;
#pragma unroll
            for (int it = 0; it < 4; ++it) {
                const int mm = m + it * 16;
                const int gr = row0 + mm, gk = k0 + k;
                float v = (gr < M && gk < K) ? A[(long long)gr * lda + gk] : 0.f;
                As[k][mm] = v;
            }
        }
        // load B tile: 16 k x 64 n
        if (!BT) {
            const int kb = tid >> 6;    // 0..3
            const int n  = tid & 63;
#pragma unroll
            for (int it = 0; it < 4; ++it) {
                const int kk = kb + it * 4;
                const int gk = k0 + kk, gn = col0 + n;
                float v = (gk < K && gn < N) ? B[(long long)gk * ldb + gn] : 0.f;
                Bs[kk][n] = v;
            }
        } else {
            const int nb = tid >> 4;    // 0..15
            const int k  = tid & 15;
#pragma unroll
            for (int it = 0; it < 4; ++it) {
                const int nn = nb + it * 16;
                const int gn = col0 + nn, gk = k0 + k;
                float v = (gn < N && gk < K) ? B[(long long)gn * ldb + gk] : 0.f;
                Bs[k][nn] = v;
            }
        }
        __syncthreads();

#pragma unroll
        for (int k = 0; k < 16; ++k) {
            float a[4], b[4];
#pragma unroll
            for (int i = 0; i < 4; ++i) a[i] = As[k][ty * 4 + i];
#pragma unroll
            for (int j = 0; j < 4; ++j) b[j] = Bs[k][tx * 4 + j];
#pragma unroll
            for (int i = 0; i < 4; ++i)
#pragma unroll
                for (int j = 0; j < 4; ++j)
                    acc[i][j] = fmaf(a[i], b[j], acc[i][j]);
        }
        __syncthreads();
    }

#pragma unroll
    for (int i = 0; i < 4; ++i) {
        const int gr = row0 + ty * 4 + i;
        if (gr >= M) continue;
#pragma unroll
        for (int j = 0; j < 4; ++j) {
            const int gn = col0 + tx * 4 + j;
            if (gn < N) C[(long long)gr * ldc + gn] = acc[i][j];
        }
    }
}

// ---------------------------------------------------------------------------
// Build augmented Q/K rows and combined V rows from projections.
//   QA[b][h][l][80] = [Q/8 (64), wc*Qp_g (12), -0.5*wc*|Qp_g|^2, 1, 0, 0]
//   KA[b][h][l][80] = [K   (64),    Kp_g (12), 1, -0.5*wc*|Kp_g|^2, 0, 0]
//   VC[b][h][l][80] = [V   (64),    Vp_g (12), 0, 0, 0, 0]
// ---------------------------------------------------------------------------
__global__ __launch_bounds__(256)
void build_aug_kernel(const float* __restrict__ P, const float* __restrict__ Rm,
                      const float* __restrict__ tr, const float* __restrict__ wC,
                      float* __restrict__ QA, float* __restrict__ KA,
                      float* __restrict__ VC)
{
    const int bl = blockIdx.x;             // 0..2047
    const int b = bl >> 10, l = bl & 1023;
    const int t = threadIdx.x;

    __shared__ float g[3][NHEAD][4][3];    // proj(Q,K,V points), head, point, xyz
    __shared__ float nrm[2][NHEAD];
    __shared__ float Rloc[9], trloc[3], wcl[NHEAD];

    if (t < 9) Rloc[t] = Rm[(long long)bl * 9 + t];
    if (t < 3) trloc[t] = tr[(long long)bl * 3 + t];
    if (t < NHEAD) {
        float x = wC[t];
        wcl[t] = (x > 20.f) ? x : log1pf(expf(x));   // softplus
    }
    __syncthreads();

    const float* Prow = P + (long long)bl * PDIM;

    if (t < 96) {
        const int proj = t / 32, tpl = t % 32, h = tpl >> 2, p = tpl & 3;
        const float* src = Prow + 1536 + proj * 96 + h * 12 + p * 3;
        const float x = src[0], y = src[1], z = src[2];
        g[proj][h][p][0] = Rloc[0]*x + Rloc[1]*y + Rloc[2]*z + trloc[0];
        g[proj][h][p][1] = Rloc[3]*x + Rloc[4]*y + Rloc[5]*z + trloc[1];
        g[proj][h][p][2] = Rloc[6]*x + Rloc[7]*y + Rloc[8]*z + trloc[2];
    }
    __syncthreads();

    if (t < 16) {
        const int proj = t >> 3, h = t & 7;
        float s2 = 0.f;
#pragma unroll
        for (int p = 0; p < 4; ++p)
#pragma unroll
            for (int c = 0; c < 3; ++c) { float v = g[proj][h][p][c]; s2 += v * v; }
        nrm[proj][h] = s2;
    }
    __syncthreads();

    for (int w = t; w < NHEAD * AUGW; w += 256) {
        const int h = w / AUGW, col = w % AUGW;
        const long long rowoff = ((((long long)b * NHEAD + h) * LSEQ) + l) * AUGW;
        const float wc = wcl[h];
        float qv, kv, vv;
        if (col < 64) {
            qv = Prow[h * 64 + col] * 0.125f;
            kv = Prow[512 + h * 64 + col];
            vv = Prow[1024 + h * 64 + col];
        } else if (col < 76) {
            const int pc = col - 64, p = pc / 3, c = pc % 3;
            qv = wc * g[0][h][p][c];
            kv = g[1][h][p][c];
            vv = g[2][h][p][c];
        } else if (col == 76) {
            qv = -0.5f * wc * nrm[0][h];
            kv = 1.0f;
            vv = 0.f;
        } else if (col == 77) {
            qv = 1.0f;
            kv = -0.5f * wc * nrm[1][h];
            vv = 0.f;
        } else {
            qv = kv = vv = 0.f;
        }
        QA[rowoff + col] = qv;
        KA[rowoff + col] = kv;
        VC[rowoff + col] = vv;
    }
}

// ---------------------------------------------------------------------------
// Row softmax in place. One block per row of length L.
// ---------------------------------------------------------------------------
__global__ __launch_bounds__(256)
void softmax_kernel(float* __restrict__ S)
{
    float* p = S + (long long)blockIdx.x * LSEQ;
    const int t = threadIdx.x;
    const int wid = t >> 6, lane = t & 63;

    float mx = -1e30f;
    for (int j = t; j < LSEQ; j += 256) mx = fmaxf(mx, p[j]);
#pragma unroll
    for (int o = 32; o > 0; o >>= 1) mx = fmaxf(mx, __shfl_xor(mx, o));
    __shared__ float red[4];
    if (lane == 0) red[wid] = mx;
    __syncthreads();
    mx = fmaxf(fmaxf(red[0], red[1]), fmaxf(red[2], red[3]));

    float sum = 0.f;
    for (int j = t; j < LSEQ; j += 256) {
        float e = expf(p[j] - mx);
        p[j] = e;
        sum += e;
    }
#pragma unroll
    for (int o = 32; o > 0; o >>= 1) sum += __shfl_xor(sum, o);
    __shared__ float red2[4];
    if (lane == 0) red2[wid] = sum;
    __syncthreads();
    sum = red2[0] + red2[1] + red2[2] + red2[3];
    const float inv = 1.0f / sum;
    for (int j = t; j < LSEQ; j += 256) p[j] *= inv;
}

// ---------------------------------------------------------------------------
// Gather attn output, un-rotate points, build concat rows CC[2048][608].
// ---------------------------------------------------------------------------
__global__ __launch_bounds__(256)
void build_concat_kernel(const float* __restrict__ OC, const float* __restrict__ Rm,
                         const float* __restrict__ tr, float* __restrict__ CC)
{
    const int bl = blockIdx.x;
    const int b = bl >> 10, l = bl & 1023;
    const int t = threadIdx.x;

    __shared__ float Rloc[9], trloc[3];
    if (t < 9) Rloc[t] = Rm[(long long)bl * 9 + t];
    if (t < 3) trloc[t] = tr[(long long)bl * 3 + t];
    __syncthreads();

    float* crow = CC + (long long)bl * ODIM;

    for (int w = t; w < DMODEL; w += 256) {
        const int h = w >> 6, d = w & 63;
        crow[w] = OC[((((long long)b * NHEAD + h) * LSEQ) + l) * AUGW + d];
    }
    if (t < 32) {
        const int h = t >> 2, p = t & 3;
        const float* o = OC + ((((long long)b * NHEAD + h) * LSEQ) + l) * AUGW + 64 + p * 3;
        const float x = o[0] - trloc[0], y = o[1] - trloc[1], z = o[2] - trloc[2];
        // Vp_local[x] = sum_y R[y][x] * v[y]   (R^T)
        crow[512 + h * 12 + p * 3 + 0] = Rloc[0]*x + Rloc[3]*y + Rloc[6]*z;
        crow[512 + h * 12 + p * 3 + 1] = Rloc[1]*x + Rloc[4]*y + Rloc[7]*z;
        crow[512 + h * 12 + p * 3 + 2] = Rloc[2]*x + Rloc[5]*y + Rloc[8]*z;
    }
}

// ---------------------------------------------------------------------------
// out = LayerNorm(s + Y + bo) * gamma + beta     (one block per row of 512)
// ---------------------------------------------------------------------------
__global__ __launch_bounds__(256)
void residual_ln_kernel(const float* __restrict__ s, const float* __restrict__ Y,
                        const float* __restrict__ bo, const float* __restrict__ gamma,
                        const float* __restrict__ beta, float* __restrict__ out)
{
    const int bl = blockIdx.x;
    const int t = threadIdx.x;
    const float* srow = s + (long long)bl * DMODEL;
    const float* yrow = Y + (long long)bl * DMODEL;

    const float v0 = srow[t]       + yrow[t]       + bo[t];
    const float v1 = srow[t + 256] + yrow[t + 256] + bo[t + 256];

    float sum = v0 + v1, sq = v0 * v0 + v1 * v1;
#pragma unroll
    for (int o = 32; o > 0; o >>= 1) {
        sum += __shfl_xor(sum, o);
        sq  += __shfl_xor(sq,  o);
    }
    __shared__ float rs[4], rq[4];
    const int wid = t >> 6, lane = t & 63;
    if (lane == 0) { rs[wid] = sum; rq[wid] = sq; }
    __syncthreads();
    sum = rs[0] + rs[1] + rs[2] + rs[3];
    sq  = rq[0] + rq[1] + rq[2] + rq[3];

    const float mu  = sum * (1.0f / DMODEL);
    const float var = sq * (1.0f / DMODEL) - mu * mu;
    const float inv = rsqrtf(var + 1e-5f);

    out[(long long)bl * DMODEL + t]       = (v0 - mu) * inv * gamma[t]       + beta[t];
    out[(long long)bl * DMODEL + t + 256] = (v1 - mu) * inv * gamma[t + 256] + beta[t + 256];
}

// ---------------------------------------------------------------------------
extern "C" void kernel_launch(void* const* d_in, const int* in_sizes, int n_in,
                              void* d_out, int out_size, void* d_ws, size_t ws_size,
                              hipStream_t stream)
{
    const float* s    = (const float*)d_in[0];
    const float* R    = (const float*)d_in[1];
    const float* tr   = (const float*)d_in[2];
    const float* Wq   = (const float*)d_in[3];
    const float* Wk   = (const float*)d_in[4];
    const float* Wv   = (const float*)d_in[5];
    const float* Wqp  = (const float*)d_in[6];
    const float* Wkp  = (const float*)d_in[7];
    const float* Wvp  = (const float*)d_in[8];
    const float* Wo   = (const float*)d_in[9];
    const float* bo   = (const float*)d_in[10];
    const float* gam  = (const float*)d_in[11];
    const float* bet  = (const float*)d_in[12];
    const float* wC   = (const float*)d_in[13];
    float* out = (float*)d_out;

    float* ws = (float*)d_ws;
    // workspace layout (floats)
    float* P  = ws;                               // [2048][1824]  (dead after build_aug)
    float* QA = ws + 3735552;                     // [2][8][1024][80]
    float* KA = QA + 1310720;
    float* VC = KA + 1310720;
    float* OC = VC + 1310720;
    float* S  = OC + 1310720;                     // [8][1024][1024], reused per batch
    float* CC = ws;                               // aliases dead P: [2048][608]
    float* Y  = ws + 1245184;                     // aliases dead P: [2048][512]

    const dim3 blk(256);

    // 1) projections: P = s @ [Wq|Wk|Wv|Wqp|Wkp|Wvp]
    gemm_f32_kernel<false><<<dim3(8, 32, 1), blk, 0, stream>>>(
        s, Wq, P + 0,    BLTOT, 512, 512, 512, 512, PDIM, 0, 0, 0);
    gemm_f32_kernel<false><<<dim3(8, 32, 1), blk, 0, stream>>>(
        s, Wk, P + 512,  BLTOT, 512, 512, 512, 512, PDIM, 0, 0, 0);
    gemm_f32_kernel<false><<<dim3(8, 32, 1), blk, 0, stream>>>(
        s, Wv, P + 1024, BLTOT, 512, 512, 512, 512, PDIM, 0, 0, 0);
    gemm_f32_kernel<false><<<dim3(2, 32, 1), blk, 0, stream>>>(
        s, Wqp, P + 1536, BLTOT, 96, 512, 512, 96, PDIM, 0, 0, 0);
    gemm_f32_kernel<false><<<dim3(2, 32, 1), blk, 0, stream>>>(
        s, Wkp, P + 1632, BLTOT, 96, 512, 512, 96, PDIM, 0, 0, 0);
    gemm_f32_kernel<false><<<dim3(2, 32, 1), blk, 0, stream>>>(
        s, Wvp, P + 1728, BLTOT, 96, 512, 512, 96, PDIM, 0, 0, 0);

    // 2) global-frame points + augmented rows
    build_aug_kernel<<<dim3(BLTOT), blk, 0, stream>>>(P, R, tr, wC, QA, KA, VC);

    // 3) attention per batch (S buffer reused)
    for (int b = 0; b < BATCH; ++b) {
        const long long aoff = (long long)b * NHEAD * LSEQ * AUGW;
        // scores: S[h] = QA[b,h] @ KA[b,h]^T   (K=80)
        gemm_f32_kernel<true><<<dim3(16, 16, NHEAD), blk, 0, stream>>>(
            QA + aoff, KA + aoff, S, LSEQ, LSEQ, AUGW,
            AUGW, AUGW, LSEQ,
            (long long)LSEQ * AUGW, (long long)LSEQ * AUGW, (long long)LSEQ * LSEQ);
        // softmax rows
        softmax_kernel<<<dim3(NHEAD * LSEQ), blk, 0, stream>>>(S);
        // weighted values: OC[b,h] = S[h] @ VC[b,h]   (N=80, K=1024)
        gemm_f32_kernel<false><<<dim3(2, 16, NHEAD), blk, 0, stream>>>(
            S, VC + aoff, OC + aoff, LSEQ, AUGW, LSEQ,
            LSEQ, AUGW, AUGW,
            (long long)LSEQ * LSEQ, (long long)LSEQ * AUGW, (long long)LSEQ * AUGW);
    }

    // 4) un-rotate + concat
    build_concat_kernel<<<dim3(BLTOT), blk, 0, stream>>>(OC, R, tr, CC);

    // 5) output projection: Y = CC @ Wo
    gemm_f32_kernel<false><<<dim3(8, 32, 1), blk, 0, stream>>>(
        CC, Wo, Y, BLTOT, 512, ODIM, ODIM, 512, 512, 0, 0, 0);

    // 6) residual + layernorm
    residual_ln_kernel<<<dim3(BLTOT), blk, 0, stream>>>(s, Y, bo, gam, bet, out);
}

// Round 2
// 106.517 us; speedup vs baseline: 9.7357x; 9.7357x over previous
//
#include <hip/hip_runtime.h>
#include <hip/hip_fp16.h>
#include <math.h>

typedef _Float16 f16;
typedef _Float16 f16x8 __attribute__((ext_vector_type(8)));
typedef _Float16 f16x4v __attribute__((ext_vector_type(4)));
typedef float f32x4 __attribute__((ext_vector_type(4)));

#define BATCH   2
#define LSEQ    1024
#define BLTOT   2048
#define DMODEL  512
#define NHEAD   8
#define PDIM    1824          // 512*3 + 96*3
#define AW      96            // augmented width (76 used, padded to 96)
#define ODIM    608
#define QBLK    64
#define KVBLK   64

// ---------------------------------------------------------------------------
// s (f32) -> f16
// ---------------------------------------------------------------------------
__global__ __launch_bounds__(256)
void convert_s_kernel(const float* __restrict__ s, f16* __restrict__ out)
{
    const int i = blockIdx.x * 256 + threadIdx.x;   // over float4 chunks
    float4 v = ((const float4*)s)[i];
    f16x4v o = { (f16)v.x, (f16)v.y, (f16)v.z, (f16)v.w };
    ((f16x4v*)out)[i] = o;
}

// ---------------------------------------------------------------------------
// Build WallT[1824][512] f16 = concat(Wq,Wk,Wv,Wqp,Wkp,Wvp) transposed.
// blockIdx.x = n-tile (57), blockIdx.y = k-tile (16). 32x32 tiles.
// ---------------------------------------------------------------------------
__global__ __launch_bounds__(256)
void transpose_wall_kernel(const float* __restrict__ Wq, const float* __restrict__ Wk,
                           const float* __restrict__ Wv, const float* __restrict__ Wqp,
                           const float* __restrict__ Wkp, const float* __restrict__ Wvp,
                           f16* __restrict__ WT)
{
    const int n0 = blockIdx.x * 32, k0 = blockIdx.y * 32;
    const int t = threadIdx.x;
    const float* src; int ld, nc0;
    if      (n0 < 512)  { src = Wq;  ld = 512; nc0 = n0; }
    else if (n0 < 1024) { src = Wk;  ld = 512; nc0 = n0 - 512; }
    else if (n0 < 1536) { src = Wv;  ld = 512; nc0 = n0 - 1024; }
    else if (n0 < 1632) { src = Wqp; ld = 96;  nc0 = n0 - 1536; }
    else if (n0 < 1728) { src = Wkp; ld = 96;  nc0 = n0 - 1632; }
    else                { src = Wvp; ld = 96;  nc0 = n0 - 1728; }

    __shared__ float tile[32][33];
#pragma unroll
    for (int i = 0; i < 4; ++i) {
        const int idx = t + i * 256;
        const int kl = idx >> 5, nl = idx & 31;
        tile[kl][nl] = src[(long long)(k0 + kl) * ld + nc0 + nl];
    }
    __syncthreads();
#pragma unroll
    for (int i = 0; i < 4; ++i) {
        const int idx = t + i * 256;
        const int nl = idx >> 5, kl = idx & 31;
        WT[(long long)(n0 + nl) * 512 + k0 + kl] = (f16)tile[kl][nl];
    }
}

// ---------------------------------------------------------------------------
// WoT[512][608] f16 from Wo[608][512] f32.  blockIdx.x = n-tile(16), y = k-tile(19)
// ---------------------------------------------------------------------------
__global__ __launch_bounds__(256)
void transpose_wo_kernel(const float* __restrict__ Wo, f16* __restrict__ WT)
{
    const int n0 = blockIdx.x * 32, k0 = blockIdx.y * 32;
    const int t = threadIdx.x;
    __shared__ float tile[32][33];
#pragma unroll
    for (int i = 0; i < 4; ++i) {
        const int idx = t + i * 256;
        const int kl = idx >> 5, nl = idx & 31;
        tile[kl][nl] = Wo[(long long)(k0 + kl) * 512 + n0 + nl];
    }
    __syncthreads();
#pragma unroll
    for (int i = 0; i < 4; ++i) {
        const int idx = t + i * 256;
        const int nl = idx >> 5, kl = idx & 31;
        WT[(long long)(n0 + nl) * 608 + k0 + kl] = (f16)tile[kl][nl];
    }
}

// ---------------------------------------------------------------------------
// MFMA f16 GEMM.  C[M][ldc] = A[M][K] @ Bt[N][K]^T.  Tile 128 x BN, BK=32.
// 4 waves stacked on M (32 rows each, 2 m-frags). BN/16 n-frags.
// ---------------------------------------------------------------------------
template<int BN, bool OUT16>
__global__ __launch_bounds__(256)
void gemm_f16_kernel(const f16* __restrict__ A, const f16* __restrict__ Bt,
                     void* __restrict__ Cout, int K, int ldc)
{
    __shared__ f16 As[128][40];
    __shared__ f16 Bs[BN][40];
    const int t = threadIdx.x;
    const int w = t >> 6, lane = t & 63, l15 = lane & 15, lhi = lane >> 4;
    const int row0 = blockIdx.y * 128, col0 = blockIdx.x * BN;

    f32x4 acc[2][BN / 16];
#pragma unroll
    for (int m = 0; m < 2; ++m)
#pragma unroll
        for (int n = 0; n < BN / 16; ++n)
            acc[m][n] = (f32x4){0.f, 0.f, 0.f, 0.f};

    const int nsteps = K >> 5;
    for (int st = 0; st < nsteps; ++st) {
        const int k0 = st << 5;
#pragma unroll
        for (int i = 0; i < 2; ++i) {
            const int cid = t + i * 256;          // 512 chunks
            const int r = cid >> 2, c = cid & 3;
            *(f16x8*)&As[r][c * 8] =
                *(const f16x8*)&A[(long long)(row0 + r) * K + k0 + c * 8];
        }
#pragma unroll
        for (int i = 0; i < (BN * 4 + 255) / 256; ++i) {
            const int cid = t + i * 256;
            if (cid < BN * 4) {
                const int r = cid >> 2, c = cid & 3;
                *(f16x8*)&Bs[r][c * 8] =
                    *(const f16x8*)&Bt[(long long)(col0 + r) * K + k0 + c * 8];
            }
        }
        __syncthreads();
        f16x8 af[2], bf[BN / 16];
#pragma unroll
        for (int m = 0; m < 2; ++m)
            af[m] = *(const f16x8*)&As[w * 32 + m * 16 + l15][lhi * 8];
#pragma unroll
        for (int n = 0; n < BN / 16; ++n)
            bf[n] = *(const f16x8*)&Bs[n * 16 + l15][lhi * 8];
#pragma unroll
        for (int m = 0; m < 2; ++m)
#pragma unroll
            for (int n = 0; n < BN / 16; ++n)
                acc[m][n] = __builtin_amdgcn_mfma_f32_16x16x32_f16(af[m], bf[n], acc[m][n], 0, 0, 0);
        __syncthreads();
    }
#pragma unroll
    for (int m = 0; m < 2; ++m) {
        const int row = row0 + w * 32 + m * 16 + lhi * 4;
#pragma unroll
        for (int n = 0; n < BN / 16; ++n) {
            const int col = col0 + n * 16 + l15;
#pragma unroll
            for (int r = 0; r < 4; ++r) {
                if (OUT16) ((f16*)Cout)[(long long)(row + r) * ldc + col] = (f16)acc[m][n][r];
                else       ((float*)Cout)[(long long)(row + r) * ldc + col] = acc[m][n][r];
            }
        }
    }
}

// ---------------------------------------------------------------------------
// Augment: P f16 [2048][1824] -> QA/KA f16 [16][1024][96], VCT f16 [16][96][1024],
// KOFF f32 [16][1024].
//   QA: [Q/8 (64), wc*qg (12), 0...]   KA: [K (64), kg (12), 0...]
//   VCT[c][l]: c<64: V[c]; 64..75: vg; else 0.   KOFF = 0.5*wc*|kg|^2
// ---------------------------------------------------------------------------
__global__ __launch_bounds__(256)
void build_aug_kernel(const f16* __restrict__ P, const float* __restrict__ Rm,
                      const float* __restrict__ tr, const float* __restrict__ wC,
                      f16* __restrict__ QA, f16* __restrict__ KA,
                      f16* __restrict__ VCT, float* __restrict__ KOFF)
{
    const int bl = blockIdx.x;
    const int b = bl >> 10, l = bl & 1023;
    const int t = threadIdx.x;

    __shared__ float g[3][NHEAD][4][3];
    __shared__ float Rloc[9], trloc[3], wcl[NHEAD];

    if (t < 9) Rloc[t] = Rm[(long long)bl * 9 + t];
    if (t < 3) trloc[t] = tr[(long long)bl * 3 + t];
    if (t < NHEAD) { float x = wC[t]; wcl[t] = log1pf(expf(x)); }
    __syncthreads();

    const f16* Prow = P + (long long)bl * PDIM;

    if (t < 96) {
        const int proj = t / 32, tpl = t % 32, h = tpl >> 2, p = tpl & 3;
        const f16* src = Prow + 1536 + proj * 96 + h * 12 + p * 3;
        const float x = (float)src[0], y = (float)src[1], z = (float)src[2];
        g[proj][h][p][0] = Rloc[0]*x + Rloc[1]*y + Rloc[2]*z + trloc[0];
        g[proj][h][p][1] = Rloc[3]*x + Rloc[4]*y + Rloc[5]*z + trloc[1];
        g[proj][h][p][2] = Rloc[6]*x + Rloc[7]*y + Rloc[8]*z + trloc[2];
    }
    __syncthreads();

    if (t < NHEAD) {
        float s2 = 0.f;
#pragma unroll
        for (int p = 0; p < 4; ++p)
#pragma unroll
            for (int c = 0; c < 3; ++c) { float v = g[1][t][p][c]; s2 += v * v; }
        KOFF[(long long)(b * NHEAD + t) * LSEQ + l] = 0.5f * wcl[t] * s2;
    }

    for (int w = t; w < NHEAD * AW; w += 256) {
        const int h = w / AW, col = w % AW;
        const long long ro = ((long long)(b * NHEAD + h) * LSEQ + l) * AW;
        float qv = 0.f, kv = 0.f;
        if (col < 64) {
            qv = (float)Prow[h * 64 + col] * 0.125f;
            kv = (float)Prow[512 + h * 64 + col];
        } else if (col < 76) {
            const int pc = col - 64, p = pc / 3, c = pc % 3;
            qv = wcl[h] * g[0][h][p][c];
            kv = g[1][h][p][c];
        }
        QA[ro + col] = (f16)qv;
        KA[ro + col] = (f16)kv;
    }

    for (int w = t; w < NHEAD * AW; w += 256) {
        const int h = w / AW, c = w % AW;
        float vv = 0.f;
        if (c < 64) vv = (float)Prow[1024 + h * 64 + c];
        else if (c < 76) { const int pc = c - 64, p = pc / 3, cc = pc % 3; vv = g[2][h][p][cc]; }
        VCT[((long long)(b * NHEAD + h) * AW + c) * LSEQ + l] = (f16)vv;
    }
}

// ---------------------------------------------------------------------------
// Fused flash attention.  Grid (16 q-tiles, 16 bh). 4 waves, each 16 Q-rows.
// ---------------------------------------------------------------------------
__global__ __launch_bounds__(256)
void attn_kernel(const f16* __restrict__ QA, const f16* __restrict__ KA,
                 const f16* __restrict__ VCT, const float* __restrict__ KOFF,
                 float* __restrict__ OC)
{
    const int bh = blockIdx.y;
    const int q0 = blockIdx.x * QBLK;
    const int t = threadIdx.x;
    const int w = t >> 6, lane = t & 63, l15 = lane & 15, lhi = lane >> 4;

    __shared__ f16 Ks[KVBLK][104];
    __shared__ f16 Vs[AW][72];
    __shared__ f16 Ps[QBLK][72];

    // Q fragments in registers (wave's 16 rows)
    const f16* qbase = QA + ((long long)bh * LSEQ + q0 + w * 16 + l15) * AW;
    f16x8 qf[3];
#pragma unroll
    for (int ks = 0; ks < 3; ++ks)
        qf[ks] = *(const f16x8*)(qbase + ks * 32 + lhi * 8);

    f32x4 Oacc[6];
#pragma unroll
    for (int nv = 0; nv < 6; ++nv) Oacc[nv] = (f32x4){0.f, 0.f, 0.f, 0.f};
    float M[4], L[4];
#pragma unroll
    for (int r = 0; r < 4; ++r) { M[r] = -1e30f; L[r] = 0.f; }

    const f16* kgbase = KA + (long long)bh * LSEQ * AW;
    const f16* vgbase = VCT + (long long)bh * AW * LSEQ;
    const float* koffb = KOFF + (long long)bh * LSEQ;

    for (int kv0 = 0; kv0 < LSEQ; kv0 += KVBLK) {
        // stage K tile: 64 rows x 12 chunks of 8 halfs = 768 chunks
#pragma unroll
        for (int i = 0; i < 3; ++i) {
            const int cid = t + i * 256;
            const int r = cid / 12, c = cid % 12;
            *(f16x8*)&Ks[r][c * 8] = *(const f16x8*)(kgbase + (long long)(kv0 + r) * AW + c * 8);
        }
        // stage V tile (transposed source): 96 rows x 8 chunks = 768
#pragma unroll
        for (int i = 0; i < 3; ++i) {
            const int cid = t + i * 256;
            const int r = cid >> 3, c = cid & 7;
            *(f16x8*)&Vs[r][c * 8] = *(const f16x8*)(vgbase + (long long)r * LSEQ + kv0 + c * 8);
        }
        __syncthreads();

        // S = QA @ K^T  (64 cols of this tile per wave's 16 rows)
        f32x4 sc[4];
#pragma unroll
        for (int n = 0; n < 4; ++n) sc[n] = (f32x4){0.f, 0.f, 0.f, 0.f};
#pragma unroll
        for (int n = 0; n < 4; ++n)
#pragma unroll
            for (int ks = 0; ks < 3; ++ks) {
                f16x8 kb = *(const f16x8*)&Ks[n * 16 + l15][ks * 32 + lhi * 8];
                sc[n] = __builtin_amdgcn_mfma_f32_16x16x32_f16(qf[ks], kb, sc[n], 0, 0, 0);
            }
        // subtract 0.5*wc*|kg_j|^2 (f32, per column)
#pragma unroll
        for (int n = 0; n < 4; ++n) {
            const float ko = koffb[kv0 + n * 16 + l15];
#pragma unroll
            for (int r = 0; r < 4; ++r) sc[n][r] -= ko;
        }
        // online softmax
        float sscale[4];
#pragma unroll
        for (int r = 0; r < 4; ++r) {
            float mr = fmaxf(fmaxf(sc[0][r], sc[1][r]), fmaxf(sc[2][r], sc[3][r]));
#pragma unroll
            for (int off = 1; off < 16; off <<= 1) mr = fmaxf(mr, __shfl_xor(mr, off));
            const float nm = fmaxf(M[r], mr);
            sscale[r] = __expf(M[r] - nm);
            M[r] = nm;
        }
        float rsum[4] = {0.f, 0.f, 0.f, 0.f};
#pragma unroll
        for (int n = 0; n < 4; ++n)
#pragma unroll
            for (int r = 0; r < 4; ++r) {
                const float p = __expf(sc[n][r] - M[r]);
                sc[n][r] = p;
                rsum[r] += p;
            }
#pragma unroll
        for (int r = 0; r < 4; ++r) {
            float s = rsum[r];
#pragma unroll
            for (int off = 1; off < 16; off <<= 1) s += __shfl_xor(s, off);
            L[r] = L[r] * sscale[r] + s;
        }
#pragma unroll
        for (int nv = 0; nv < 6; ++nv)
#pragma unroll
            for (int r = 0; r < 4; ++r) Oacc[nv][r] *= sscale[r];

        // P -> LDS (own wave's rows only)
#pragma unroll
        for (int n = 0; n < 4; ++n)
#pragma unroll
            for (int r = 0; r < 4; ++r)
                Ps[w * 16 + lhi * 4 + r][n * 16 + l15] = (f16)sc[n][r];

        // PV (reads own wave's P rows; compiler inserts lgkm waits)
        f16x8 pa[2];
#pragma unroll
        for (int ks = 0; ks < 2; ++ks)
            pa[ks] = *(const f16x8*)&Ps[w * 16 + l15][ks * 32 + lhi * 8];
#pragma unroll
        for (int nv = 0; nv < 6; ++nv)
#pragma unroll
            for (int ks = 0; ks < 2; ++ks) {
                f16x8 vb = *(const f16x8*)&Vs[nv * 16 + l15][ks * 32 + lhi * 8];
                Oacc[nv] = __builtin_amdgcn_mfma_f32_16x16x32_f16(pa[ks], vb, Oacc[nv], 0, 0, 0);
            }
        __syncthreads();
    }

    float inv[4];
#pragma unroll
    for (int r = 0; r < 4; ++r) inv[r] = 1.0f / L[r];
    float* obase = OC + ((long long)bh * LSEQ + q0 + w * 16) * AW;
#pragma unroll
    for (int nv = 0; nv < 6; ++nv)
#pragma unroll
        for (int r = 0; r < 4; ++r)
            obase[(lhi * 4 + r) * AW + nv * 16 + l15] = Oacc[nv][r] * inv[r];
}

// ---------------------------------------------------------------------------
// Un-rotate + concat -> CC f16 [2048][608]
// ---------------------------------------------------------------------------
__global__ __launch_bounds__(256)
void build_concat_kernel(const float* __restrict__ OC, const float* __restrict__ Rm,
                         const float* __restrict__ tr, f16* __restrict__ CC)
{
    const int bl = blockIdx.x;
    const int b = bl >> 10, l = bl & 1023;
    const int t = threadIdx.x;

    __shared__ float Rloc[9], trloc[3];
    if (t < 9) Rloc[t] = Rm[(long long)bl * 9 + t];
    if (t < 3) trloc[t] = tr[(long long)bl * 3 + t];
    __syncthreads();

    f16* crow = CC + (long long)bl * ODIM;

    for (int w = t; w < DMODEL; w += 256) {
        const int h = w >> 6, d = w & 63;
        crow[w] = (f16)OC[((long long)(b * NHEAD + h) * LSEQ + l) * AW + d];
    }
    if (t < 32) {
        const int h = t >> 2, p = t & 3;
        const float* o = OC + ((long long)(b * NHEAD + h) * LSEQ + l) * AW + 64 + p * 3;
        const float x = o[0] - trloc[0], y = o[1] - trloc[1], z = o[2] - trloc[2];
        crow[512 + h * 12 + p * 3 + 0] = (f16)(Rloc[0]*x + Rloc[3]*y + Rloc[6]*z);
        crow[512 + h * 12 + p * 3 + 1] = (f16)(Rloc[1]*x + Rloc[4]*y + Rloc[7]*z);
        crow[512 + h * 12 + p * 3 + 2] = (f16)(Rloc[2]*x + Rloc[5]*y + Rloc[8]*z);
    }
}

// ---------------------------------------------------------------------------
// out = LayerNorm(s + Y + bo) * gamma + beta
// ---------------------------------------------------------------------------
__global__ __launch_bounds__(256)
void residual_ln_kernel(const float* __restrict__ s, const float* __restrict__ Y,
                        const float* __restrict__ bo, const float* __restrict__ gamma,
                        const float* __restrict__ beta, float* __restrict__ out)
{
    const int bl = blockIdx.x;
    const int t = threadIdx.x;
    const float* srow = s + (long long)bl * DMODEL;
    const float* yrow = Y + (long long)bl * DMODEL;

    const float v0 = srow[t]       + yrow[t]       + bo[t];
    const float v1 = srow[t + 256] + yrow[t + 256] + bo[t + 256];

    float sum = v0 + v1, sq = v0 * v0 + v1 * v1;
#pragma unroll
    for (int o = 32; o > 0; o >>= 1) {
        sum += __shfl_xor(sum, o);
        sq  += __shfl_xor(sq,  o);
    }
    __shared__ float rs[4], rq[4];
    const int wid = t >> 6, lane = t & 63;
    if (lane == 0) { rs[wid] = sum; rq[wid] = sq; }
    __syncthreads();
    sum = rs[0] + rs[1] + rs[2] + rs[3];
    sq  = rq[0] + rq[1] + rq[2] + rq[3];

    const float mu  = sum * (1.0f / DMODEL);
    const float var = sq * (1.0f / DMODEL) - mu * mu;
    const float inv = rsqrtf(var + 1e-5f);

    out[(long long)bl * DMODEL + t]       = (v0 - mu) * inv * gamma[t]       + beta[t];
    out[(long long)bl * DMODEL + t + 256] = (v1 - mu) * inv * gamma[t + 256] + beta[t + 256];
}

// ---------------------------------------------------------------------------
extern "C" void kernel_launch(void* const* d_in, const int* in_sizes, int n_in,
                              void* d_out, int out_size, void* d_ws, size_t ws_size,
                              hipStream_t stream)
{
    const float* s    = (const float*)d_in[0];
    const float* R    = (const float*)d_in[1];
    const float* tr   = (const float*)d_in[2];
    const float* Wq   = (const float*)d_in[3];
    const float* Wk   = (const float*)d_in[4];
    const float* Wv   = (const float*)d_in[5];
    const float* Wqp  = (const float*)d_in[6];
    const float* Wkp  = (const float*)d_in[7];
    const float* Wvp  = (const float*)d_in[8];
    const float* Wo   = (const float*)d_in[9];
    const float* bo   = (const float*)d_in[10];
    const float* gam  = (const float*)d_in[11];
    const float* bet  = (const float*)d_in[12];
    const float* wC   = (const float*)d_in[13];
    float* out = (float*)d_out;

    // workspace layout (f16 counts unless noted)
    f16* sH    = (f16*)d_ws;                       // 2048*512
    f16* WallT = sH + 2048 * 512;                  // 1824*512
    f16* WoT   = WallT + 1824 * 512;               // 512*608
    f16* P     = WoT + 512 * 608;                  // 2048*1824
    f16* QA    = P + 2048 * 1824;                  // 16*1024*96
    f16* KA    = QA + 16 * 1024 * 96;
    f16* VCT   = KA + 16 * 1024 * 96;
    float* KOFF = (float*)(VCT + 16 * 96 * 1024);  // 16*1024 f32
    float* OC   = KOFF + 16 * 1024;                // 16*1024*96 f32
    f16* CC     = (f16*)(OC + 16 * 1024 * 96);     // 2048*608
    float* Y    = (float*)(CC + 2048 * 608);       // 2048*512 f32

    const dim3 blk(256);

    convert_s_kernel<<<dim3(1024), blk, 0, stream>>>(s, sH);
    transpose_wall_kernel<<<dim3(57, 16), blk, 0, stream>>>(Wq, Wk, Wv, Wqp, Wkp, Wvp, WallT);
    transpose_wo_kernel<<<dim3(16, 19), blk, 0, stream>>>(Wo, WoT);

    // projections: P = sH @ WallT^T   (M=2048, N=1824, K=512)
    gemm_f16_kernel<96, true><<<dim3(19, 16), blk, 0, stream>>>(sH, WallT, P, 512, 1824);

    build_aug_kernel<<<dim3(BLTOT), blk, 0, stream>>>(P, R, tr, wC, QA, KA, VCT, KOFF);

    attn_kernel<<<dim3(16, 16), blk, 0, stream>>>(QA, KA, VCT, KOFF, OC);

    build_concat_kernel<<<dim3(BLTOT), blk, 0, stream>>>(OC, R, tr, CC);

    // output projection: Y = CC @ WoT^T  (M=2048, N=512, K=608)
    gemm_f16_kernel<64, false><<<dim3(8, 16), blk, 0, stream>>>(CC, WoT, Y, 608, 512);

    residual_ln_kernel<<<dim3(BLTOT), blk, 0, stream>>>(s, Y, bo, gam, bet, out);
}

// Round 3
// 79.575 us; speedup vs baseline: 13.0320x; 1.3386x over previous
//
#include <hip/hip_runtime.h>
#include <hip/hip_fp16.h>
#include <math.h>

typedef _Float16 f16;
typedef _Float16 f16x8 __attribute__((ext_vector_type(8)));
typedef _Float16 f16x4v __attribute__((ext_vector_type(4)));
typedef float f32x4 __attribute__((ext_vector_type(4)));

#define BATCH   2
#define LSEQ    1024
#define BLTOT   2048
#define DMODEL  512
#define NHEAD   8
#define PDIM    1824          // 512*3 + 96*3
#define AW      96            // augmented width (76 used, padded to 96)
#define ODIM    608
#define NSPLIT  2

// ---------------------------------------------------------------------------
// s (f32) -> f16
// ---------------------------------------------------------------------------
__global__ __launch_bounds__(256)
void convert_s_kernel(const float* __restrict__ s, f16* __restrict__ out)
{
    const int i = blockIdx.x * 256 + threadIdx.x;   // over float4 chunks
    float4 v = ((const float4*)s)[i];
    f16x4v o = { (f16)v.x, (f16)v.y, (f16)v.z, (f16)v.w };
    ((f16x4v*)out)[i] = o;
}

// ---------------------------------------------------------------------------
// WallT[1824][512] f16 = concat(Wq,Wk,Wv,Wqp,Wkp,Wvp) transposed.
// ---------------------------------------------------------------------------
__global__ __launch_bounds__(256)
void transpose_wall_kernel(const float* __restrict__ Wq, const float* __restrict__ Wk,
                           const float* __restrict__ Wv, const float* __restrict__ Wqp,
                           const float* __restrict__ Wkp, const float* __restrict__ Wvp,
                           f16* __restrict__ WT)
{
    const int n0 = blockIdx.x * 32, k0 = blockIdx.y * 32;
    const int t = threadIdx.x;
    const float* src; int ld, nc0;
    if      (n0 < 512)  { src = Wq;  ld = 512; nc0 = n0; }
    else if (n0 < 1024) { src = Wk;  ld = 512; nc0 = n0 - 512; }
    else if (n0 < 1536) { src = Wv;  ld = 512; nc0 = n0 - 1024; }
    else if (n0 < 1632) { src = Wqp; ld = 96;  nc0 = n0 - 1536; }
    else if (n0 < 1728) { src = Wkp; ld = 96;  nc0 = n0 - 1632; }
    else                { src = Wvp; ld = 96;  nc0 = n0 - 1728; }

    __shared__ float tile[32][33];
#pragma unroll
    for (int i = 0; i < 4; ++i) {
        const int idx = t + i * 256;
        const int kl = idx >> 5, nl = idx & 31;
        tile[kl][nl] = src[(long long)(k0 + kl) * ld + nc0 + nl];
    }
    __syncthreads();
#pragma unroll
    for (int i = 0; i < 4; ++i) {
        const int idx = t + i * 256;
        const int nl = idx >> 5, kl = idx & 31;
        WT[(long long)(n0 + nl) * 512 + k0 + kl] = (f16)tile[kl][nl];
    }
}

// ---------------------------------------------------------------------------
// WoT[512][608] f16 from Wo[608][512] f32.
// ---------------------------------------------------------------------------
__global__ __launch_bounds__(256)
void transpose_wo_kernel(const float* __restrict__ Wo, f16* __restrict__ WT)
{
    const int n0 = blockIdx.x * 32, k0 = blockIdx.y * 32;
    const int t = threadIdx.x;
    __shared__ float tile[32][33];
#pragma unroll
    for (int i = 0; i < 4; ++i) {
        const int idx = t + i * 256;
        const int kl = idx >> 5, nl = idx & 31;
        tile[kl][nl] = Wo[(long long)(k0 + kl) * 512 + n0 + nl];
    }
    __syncthreads();
#pragma unroll
    for (int i = 0; i < 4; ++i) {
        const int idx = t + i * 256;
        const int nl = idx >> 5, kl = idx & 31;
        WT[(long long)(n0 + nl) * 608 + k0 + kl] = (f16)tile[kl][nl];
    }
}

// ---------------------------------------------------------------------------
// Double-buffered MFMA f16 GEMM.  C[M][ldc] = A[M][K] @ Bt[N][K]^T.
// Tile 64 x BN, BK=32, 4 waves each 16 rows. One barrier per K-step.
// ---------------------------------------------------------------------------
template<int BN, bool OUT16>
__global__ __launch_bounds__(256)
void gemm2_kernel(const f16* __restrict__ A, const f16* __restrict__ Bt,
                  void* __restrict__ Cout, int K, int ldc)
{
    constexpr int BCH = (BN * 4 + 255) / 256;
    __shared__ f16 As[2][64][40];
    __shared__ f16 Bs[2][BN][40];
    const int t = threadIdx.x;
    const int w = t >> 6, lane = t & 63, l15 = lane & 15, lhi = lane >> 4;
    const int row0 = blockIdx.y * 64, col0 = blockIdx.x * BN;
    const int ar = t >> 2, ac = t & 3;

    f32x4 acc[BN / 16];
#pragma unroll
    for (int n = 0; n < BN / 16; ++n) acc[n] = (f32x4){0.f, 0.f, 0.f, 0.f};

    const int nsteps = K >> 5;

    f16x8 aR;
    f16x8 bR[BCH];
    aR = *(const f16x8*)&A[(long long)(row0 + ar) * K + ac * 8];
#pragma unroll
    for (int i = 0; i < BCH; ++i) {
        const int cid = t + i * 256;
        if (cid < BN * 4) {
            const int br = cid >> 2, bc = cid & 3;
            bR[i] = *(const f16x8*)&Bt[(long long)(col0 + br) * K + bc * 8];
        }
    }
    *(f16x8*)&As[0][ar][ac * 8] = aR;
#pragma unroll
    for (int i = 0; i < BCH; ++i) {
        const int cid = t + i * 256;
        if (cid < BN * 4) *(f16x8*)&Bs[0][cid >> 2][(cid & 3) * 8] = bR[i];
    }
    __syncthreads();

    for (int st = 0; st < nsteps; ++st) {
        const int cur = st & 1;
        if (st + 1 < nsteps) {
            const int k0 = (st + 1) << 5;
            aR = *(const f16x8*)&A[(long long)(row0 + ar) * K + k0 + ac * 8];
#pragma unroll
            for (int i = 0; i < BCH; ++i) {
                const int cid = t + i * 256;
                if (cid < BN * 4) {
                    const int br = cid >> 2, bc = cid & 3;
                    bR[i] = *(const f16x8*)&Bt[(long long)(col0 + br) * K + k0 + bc * 8];
                }
            }
        }
        f16x8 af = *(const f16x8*)&As[cur][w * 16 + l15][lhi * 8];
        f16x8 bf[BN / 16];
#pragma unroll
        for (int n = 0; n < BN / 16; ++n)
            bf[n] = *(const f16x8*)&Bs[cur][n * 16 + l15][lhi * 8];
#pragma unroll
        for (int n = 0; n < BN / 16; ++n)
            acc[n] = __builtin_amdgcn_mfma_f32_16x16x32_f16(af, bf[n], acc[n], 0, 0, 0);
        if (st + 1 < nsteps) {
            *(f16x8*)&As[cur ^ 1][ar][ac * 8] = aR;
#pragma unroll
            for (int i = 0; i < BCH; ++i) {
                const int cid = t + i * 256;
                if (cid < BN * 4) *(f16x8*)&Bs[cur ^ 1][cid >> 2][(cid & 3) * 8] = bR[i];
            }
        }
        __syncthreads();
    }

    const int row = row0 + w * 16 + lhi * 4;
#pragma unroll
    for (int n = 0; n < BN / 16; ++n) {
        const int col = col0 + n * 16 + l15;
#pragma unroll
        for (int r = 0; r < 4; ++r) {
            if (OUT16) ((f16*)Cout)[(long long)(row + r) * ldc + col] = (f16)acc[n][r];
            else       ((float*)Cout)[(long long)(row + r) * ldc + col] = acc[n][r];
        }
    }
}

// ---------------------------------------------------------------------------
// Augment: P f16 [2048][1824] -> QA/KA f16 [16][1024][96], VC f16 [16][1024][96]
// (row-major, coalesced), KOFF f32 [16][1024].
// ---------------------------------------------------------------------------
__global__ __launch_bounds__(256)
void build_aug_kernel(const f16* __restrict__ P, const float* __restrict__ Rm,
                      const float* __restrict__ tr, const float* __restrict__ wC,
                      f16* __restrict__ QA, f16* __restrict__ KA,
                      f16* __restrict__ VC, float* __restrict__ KOFF)
{
    const int bl = blockIdx.x;
    const int b = bl >> 10, l = bl & 1023;
    const int t = threadIdx.x;

    __shared__ float g[3][NHEAD][4][3];
    __shared__ float Rloc[9], trloc[3], wcl[NHEAD];

    if (t < 9) Rloc[t] = Rm[(long long)bl * 9 + t];
    if (t < 3) trloc[t] = tr[(long long)bl * 3 + t];
    if (t < NHEAD) { float x = wC[t]; wcl[t] = log1pf(expf(x)); }
    __syncthreads();

    const f16* Prow = P + (long long)bl * PDIM;

    if (t < 96) {
        const int proj = t / 32, tpl = t % 32, h = tpl >> 2, p = tpl & 3;
        const f16* src = Prow + 1536 + proj * 96 + h * 12 + p * 3;
        const float x = (float)src[0], y = (float)src[1], z = (float)src[2];
        g[proj][h][p][0] = Rloc[0]*x + Rloc[1]*y + Rloc[2]*z + trloc[0];
        g[proj][h][p][1] = Rloc[3]*x + Rloc[4]*y + Rloc[5]*z + trloc[1];
        g[proj][h][p][2] = Rloc[6]*x + Rloc[7]*y + Rloc[8]*z + trloc[2];
    }
    __syncthreads();

    if (t < NHEAD) {
        float s2 = 0.f;
#pragma unroll
        for (int p = 0; p < 4; ++p)
#pragma unroll
            for (int c = 0; c < 3; ++c) { float v = g[1][t][p][c]; s2 += v * v; }
        KOFF[(long long)(b * NHEAD + t) * LSEQ + l] = 0.5f * wcl[t] * s2;
    }

    for (int w = t; w < NHEAD * AW; w += 256) {
        const int h = w / AW, col = w % AW;
        const long long ro = ((long long)(b * NHEAD + h) * LSEQ + l) * AW;
        const float wc = wcl[h];
        float qv = 0.f, kv = 0.f, vv = 0.f;
        if (col < 64) {
            qv = (float)Prow[h * 64 + col] * 0.125f;
            kv = (float)Prow[512 + h * 64 + col];
            vv = (float)Prow[1024 + h * 64 + col];
        } else if (col < 76) {
            const int pc = col - 64, p = pc / 3, c = pc % 3;
            qv = wc * g[0][h][p][c];
            kv = g[1][h][p][c];
            vv = g[2][h][p][c];
        }
        QA[ro + col] = (f16)qv;
        KA[ro + col] = (f16)kv;
        VC[ro + col] = (f16)vv;
    }
}

// ---------------------------------------------------------------------------
// VCT[bh][96][1024] from VC[bh][1024][96] — tiled LDS transpose.
// grid (8 l-tiles of 128, 16 bh)
// ---------------------------------------------------------------------------
__global__ __launch_bounds__(256)
void transpose_vct_kernel(const f16* __restrict__ VC, f16* __restrict__ VCT)
{
    const int bh = blockIdx.y, l0 = blockIdx.x * 128;
    const int t = threadIdx.x;
    __shared__ f16 tile[128][104];
#pragma unroll
    for (int i = 0; i < 6; ++i) {
        const int cid = t + i * 256;
        const int r = cid / 12, c = cid - r * 12;
        *(f16x8*)&tile[r][c * 8] =
            *(const f16x8*)&VC[((long long)bh * LSEQ + l0 + r) * AW + c * 8];
    }
    __syncthreads();
#pragma unroll
    for (int i = 0; i < 6; ++i) {
        const int cid = t + i * 256;
        const int r = cid >> 4, lg = cid & 15;
        f16x8 v;
#pragma unroll
        for (int j = 0; j < 8; ++j) v[j] = tile[lg * 8 + j][r];
        *(f16x8*)&VCT[((long long)bh * AW + r) * LSEQ + l0 + lg * 8] = v;
    }
}

// ---------------------------------------------------------------------------
// Fused flash attention, split-KV. Grid (16 q-tiles, 16 bh, NSPLIT).
// 4 waves, each 16 Q-rows. KVBLK=128. Outputs unnormalized O + (M,L).
// ---------------------------------------------------------------------------
__global__ __launch_bounds__(256)
void attn_kernel(const f16* __restrict__ QA, const f16* __restrict__ KA,
                 const f16* __restrict__ VCT, const float* __restrict__ KOFF,
                 float* __restrict__ OCp, float2* __restrict__ ML)
{
    const int bh = blockIdx.y;
    const int q0 = blockIdx.x * 64;
    const int z  = blockIdx.z;
    const int t = threadIdx.x;
    const int w = t >> 6, lane = t & 63, l15 = lane & 15, lhi = lane >> 4;

    __shared__ f16 Ks[128][104];
    __shared__ f16 Vs[96][136];
    __shared__ f16 Ps[64][136];

    const f16* qbase = QA + ((long long)bh * LSEQ + q0 + w * 16 + l15) * AW;
    f16x8 qf[3];
#pragma unroll
    for (int ks = 0; ks < 3; ++ks)
        qf[ks] = *(const f16x8*)(qbase + ks * 32 + lhi * 8);

    f32x4 Oacc[6];
#pragma unroll
    for (int nv = 0; nv < 6; ++nv) Oacc[nv] = (f32x4){0.f, 0.f, 0.f, 0.f};
    float M[4], L[4];
#pragma unroll
    for (int r = 0; r < 4; ++r) { M[r] = -1e30f; L[r] = 0.f; }

    const f16* kgbase = KA + (long long)bh * LSEQ * AW;
    const f16* vgbase = VCT + (long long)bh * AW * LSEQ;
    const float* koffb = KOFF + (long long)bh * LSEQ;

    const int kvbeg = z * (LSEQ / NSPLIT);
    const int kvend = kvbeg + LSEQ / NSPLIT;

    for (int kv0 = kvbeg; kv0 < kvend; kv0 += 128) {
        // stage K tile: 128 rows x 12 chunks = 1536
#pragma unroll
        for (int i = 0; i < 6; ++i) {
            const int cid = t + i * 256;
            const int r = cid / 12, c = cid - r * 12;
            *(f16x8*)&Ks[r][c * 8] = *(const f16x8*)(kgbase + (long long)(kv0 + r) * AW + c * 8);
        }
        // stage V tile: 96 rows x 16 chunks = 1536
#pragma unroll
        for (int i = 0; i < 6; ++i) {
            const int cid = t + i * 256;
            const int r = cid >> 4, c = cid & 15;
            *(f16x8*)&Vs[r][c * 8] = *(const f16x8*)(vgbase + (long long)r * LSEQ + kv0 + c * 8);
        }
        __syncthreads();

        // S = QA @ K^T : 8 col-frags x 3 k-frags
        f32x4 sc[8];
#pragma unroll
        for (int n = 0; n < 8; ++n) sc[n] = (f32x4){0.f, 0.f, 0.f, 0.f};
        __builtin_amdgcn_s_setprio(1);
#pragma unroll
        for (int n = 0; n < 8; ++n)
#pragma unroll
            for (int ks = 0; ks < 3; ++ks) {
                f16x8 kb = *(const f16x8*)&Ks[n * 16 + l15][ks * 32 + lhi * 8];
                sc[n] = __builtin_amdgcn_mfma_f32_16x16x32_f16(qf[ks], kb, sc[n], 0, 0, 0);
            }
        __builtin_amdgcn_s_setprio(0);
#pragma unroll
        for (int n = 0; n < 8; ++n) {
            const float ko = koffb[kv0 + n * 16 + l15];
#pragma unroll
            for (int r = 0; r < 4; ++r) sc[n][r] -= ko;
        }
        // online softmax
        float sscale[4];
#pragma unroll
        for (int r = 0; r < 4; ++r) {
            float mr = sc[0][r];
#pragma unroll
            for (int n = 1; n < 8; ++n) mr = fmaxf(mr, sc[n][r]);
#pragma unroll
            for (int off = 1; off < 16; off <<= 1) mr = fmaxf(mr, __shfl_xor(mr, off));
            const float nm = fmaxf(M[r], mr);
            sscale[r] = __expf(M[r] - nm);
            M[r] = nm;
        }
        float rsum[4] = {0.f, 0.f, 0.f, 0.f};
#pragma unroll
        for (int n = 0; n < 8; ++n)
#pragma unroll
            for (int r = 0; r < 4; ++r) {
                const float p = __expf(sc[n][r] - M[r]);
                sc[n][r] = p;
                rsum[r] += p;
            }
#pragma unroll
        for (int r = 0; r < 4; ++r) {
            float s = rsum[r];
#pragma unroll
            for (int off = 1; off < 16; off <<= 1) s += __shfl_xor(s, off);
            L[r] = L[r] * sscale[r] + s;
        }
#pragma unroll
        for (int nv = 0; nv < 6; ++nv)
#pragma unroll
            for (int r = 0; r < 4; ++r) Oacc[nv][r] *= sscale[r];

        // P -> LDS (own wave's rows only; in-wave RAW handled by lgkmcnt)
#pragma unroll
        for (int n = 0; n < 8; ++n)
#pragma unroll
            for (int r = 0; r < 4; ++r)
                Ps[w * 16 + lhi * 4 + r][n * 16 + l15] = (f16)sc[n][r];

        f16x8 pa[4];
#pragma unroll
        for (int ks = 0; ks < 4; ++ks)
            pa[ks] = *(const f16x8*)&Ps[w * 16 + l15][ks * 32 + lhi * 8];
        __builtin_amdgcn_s_setprio(1);
#pragma unroll
        for (int nv = 0; nv < 6; ++nv)
#pragma unroll
            for (int ks = 0; ks < 4; ++ks) {
                f16x8 vb = *(const f16x8*)&Vs[nv * 16 + l15][ks * 32 + lhi * 8];
                Oacc[nv] = __builtin_amdgcn_mfma_f32_16x16x32_f16(pa[ks], vb, Oacc[nv], 0, 0, 0);
            }
        __builtin_amdgcn_s_setprio(0);
        __syncthreads();
    }

    float* obase = OCp + (((long long)(z * 16 + bh) * LSEQ) + q0 + w * 16 + lhi * 4) * AW;
#pragma unroll
    for (int nv = 0; nv < 6; ++nv)
#pragma unroll
        for (int r = 0; r < 4; ++r)
            obase[r * AW + nv * 16 + l15] = Oacc[nv][r];
    if (l15 == 0) {
#pragma unroll
        for (int r = 0; r < 4; ++r)
            ML[(long long)(z * 16 + bh) * LSEQ + q0 + w * 16 + lhi * 4 + r] =
                make_float2(M[r], L[r]);
    }
}

// ---------------------------------------------------------------------------
// Combine splits (LSE merge) + un-rotate + concat -> CC f16 [2048][608]
// ---------------------------------------------------------------------------
__global__ __launch_bounds__(256)
void combine_concat_kernel(const float* __restrict__ OCp, const float2* __restrict__ ML,
                           const float* __restrict__ Rm, const float* __restrict__ tr,
                           f16* __restrict__ CC)
{
    const int bl = blockIdx.x;
    const int b = bl >> 10, l = bl & 1023;
    const int t = threadIdx.x;

    __shared__ float w1[8], w2[8];
    __shared__ float o[8][AW];
    __shared__ float Rloc[9], trloc[3];
    if (t < 9) Rloc[t] = Rm[(long long)bl * 9 + t];
    if (t < 3) trloc[t] = tr[(long long)bl * 3 + t];
    if (t < 8) {
        const int bh = b * 8 + t;
        const float2 m1 = ML[(long long)bh * LSEQ + l];
        const float2 m2 = ML[(long long)(16 + bh) * LSEQ + l];
        const float mm = fmaxf(m1.x, m2.x);
        const float e1 = __expf(m1.x - mm), e2 = __expf(m2.x - mm);
        const float inv = 1.0f / (m1.y * e1 + m2.y * e2);
        w1[t] = e1 * inv; w2[t] = e2 * inv;
    }
    __syncthreads();
    for (int idx = t; idx < 8 * AW; idx += 256) {
        const int h = idx / AW, c = idx - h * AW;
        const float* p1 = OCp + ((long long)(b * 8 + h) * LSEQ + l) * AW;
        const float* p2 = OCp + ((long long)(16 + b * 8 + h) * LSEQ + l) * AW;
        o[h][c] = p1[c] * w1[h] + p2[c] * w2[h];
    }
    __syncthreads();

    f16* crow = CC + (long long)bl * ODIM;
    for (int c = t; c < DMODEL; c += 256) crow[c] = (f16)o[c >> 6][c & 63];
    if (t < 32) {
        const int h = t >> 2, p = t & 3;
        const float x = o[h][64 + p * 3 + 0] - trloc[0];
        const float y = o[h][64 + p * 3 + 1] - trloc[1];
        const float z = o[h][64 + p * 3 + 2] - trloc[2];
        crow[512 + h * 12 + p * 3 + 0] = (f16)(Rloc[0]*x + Rloc[3]*y + Rloc[6]*z);
        crow[512 + h * 12 + p * 3 + 1] = (f16)(Rloc[1]*x + Rloc[4]*y + Rloc[7]*z);
        crow[512 + h * 12 + p * 3 + 2] = (f16)(Rloc[2]*x + Rloc[5]*y + Rloc[8]*z);
    }
}

// ---------------------------------------------------------------------------
// out = LayerNorm(s + Y + bo) * gamma + beta
// ---------------------------------------------------------------------------
__global__ __launch_bounds__(256)
void residual_ln_kernel(const float* __restrict__ s, const float* __restrict__ Y,
                        const float* __restrict__ bo, const float* __restrict__ gamma,
                        const float* __restrict__ beta, float* __restrict__ out)
{
    const int bl = blockIdx.x;
    const int t = threadIdx.x;
    const float* srow = s + (long long)bl * DMODEL;
    const float* yrow = Y + (long long)bl * DMODEL;

    const float v0 = srow[t]       + yrow[t]       + bo[t];
    const float v1 = srow[t + 256] + yrow[t + 256] + bo[t + 256];

    float sum = v0 + v1, sq = v0 * v0 + v1 * v1;
#pragma unroll
    for (int o = 32; o > 0; o >>= 1) {
        sum += __shfl_xor(sum, o);
        sq  += __shfl_xor(sq,  o);
    }
    __shared__ float rs[4], rq[4];
    const int wid = t >> 6, lane = t & 63;
    if (lane == 0) { rs[wid] = sum; rq[wid] = sq; }
    __syncthreads();
    sum = rs[0] + rs[1] + rs[2] + rs[3];
    sq  = rq[0] + rq[1] + rq[2] + rq[3];

    const float mu  = sum * (1.0f / DMODEL);
    const float var = sq * (1.0f / DMODEL) - mu * mu;
    const float inv = rsqrtf(var + 1e-5f);

    out[(long long)bl * DMODEL + t]       = (v0 - mu) * inv * gamma[t]       + beta[t];
    out[(long long)bl * DMODEL + t + 256] = (v1 - mu) * inv * gamma[t + 256] + beta[t + 256];
}

// ---------------------------------------------------------------------------
extern "C" void kernel_launch(void* const* d_in, const int* in_sizes, int n_in,
                              void* d_out, int out_size, void* d_ws, size_t ws_size,
                              hipStream_t stream)
{
    const float* s    = (const float*)d_in[0];
    const float* R    = (const float*)d_in[1];
    const float* tr   = (const float*)d_in[2];
    const float* Wq   = (const float*)d_in[3];
    const float* Wk   = (const float*)d_in[4];
    const float* Wv   = (const float*)d_in[5];
    const float* Wqp  = (const float*)d_in[6];
    const float* Wkp  = (const float*)d_in[7];
    const float* Wvp  = (const float*)d_in[8];
    const float* Wo   = (const float*)d_in[9];
    const float* bo   = (const float*)d_in[10];
    const float* gam  = (const float*)d_in[11];
    const float* bet  = (const float*)d_in[12];
    const float* wC   = (const float*)d_in[13];
    float* out = (float*)d_out;

    // workspace layout
    f16* sH    = (f16*)d_ws;                       // 1,048,576
    f16* WallT = sH + 1048576;                     // 933,888
    f16* WoT   = WallT + 933888;                   // 311,296
    f16* P     = WoT + 311296;                     // 3,735,552
    f16* QA    = P + 3735552;                      // 1,572,864
    f16* KA    = QA + 1572864;
    f16* VC    = KA + 1572864;
    f16* VCT   = VC + 1572864;
    float* KOFF = (float*)(VCT + 1572864);         // 16,384 f32
    float* OCp  = KOFF + 16384;                    // 3,145,728 f32 (2 splits)
    float2* ML  = (float2*)(OCp + 3145728);        // 32,768 float2
    f16* CC     = (f16*)(ML + 32768);              // 1,245,184
    float* Y    = (float*)(CC + 1245184);          // 1,048,576 f32

    const dim3 blk(256);

    convert_s_kernel<<<dim3(1024), blk, 0, stream>>>(s, sH);
    transpose_wall_kernel<<<dim3(57, 16), blk, 0, stream>>>(Wq, Wk, Wv, Wqp, Wkp, Wvp, WallT);
    transpose_wo_kernel<<<dim3(16, 19), blk, 0, stream>>>(Wo, WoT);

    // projections: P = sH @ WallT^T   (M=2048, N=1824, K=512)
    gemm2_kernel<96, true><<<dim3(19, 32), blk, 0, stream>>>(sH, WallT, P, 512, 1824);

    build_aug_kernel<<<dim3(BLTOT), blk, 0, stream>>>(P, R, tr, wC, QA, KA, VC, KOFF);
    transpose_vct_kernel<<<dim3(8, 16), blk, 0, stream>>>(VC, VCT);

    attn_kernel<<<dim3(16, 16, NSPLIT), blk, 0, stream>>>(QA, KA, VCT, KOFF, OCp, ML);

    combine_concat_kernel<<<dim3(BLTOT), blk, 0, stream>>>(OCp, ML, R, tr, CC);

    // output projection: Y = CC @ WoT^T  (M=2048, N=512, K=608)
    gemm2_kernel<64, false><<<dim3(8, 32), blk, 0, stream>>>(CC, WoT, Y, 608, 512);

    residual_ln_kernel<<<dim3(BLTOT), blk, 0, stream>>>(s, Y, bo, gam, bet, out);
}

// Round 4
// 72.902 us; speedup vs baseline: 14.2248x; 1.0915x over previous
//
#include <hip/hip_runtime.h>
#include <hip/hip_fp16.h>
#include <math.h>

typedef _Float16 f16;
typedef _Float16 f16x8 __attribute__((ext_vector_type(8)));
typedef _Float16 f16x4v __attribute__((ext_vector_type(4)));
typedef float f32x4 __attribute__((ext_vector_type(4)));

#define BATCH   2
#define LSEQ    1024
#define BLTOT   2048
#define DMODEL  512
#define NHEAD   8
#define PDIM    1824          // 512*3 + 96*3
#define AW      96            // augmented width (76 used, padded to 96)
#define ODIM    608
#define NSPLIT  2

// ---------------------------------------------------------------------------
// Fused prep: [0,1024) convert s->f16; [1024,1936) WallT; [1936,2240) WoT.
// ---------------------------------------------------------------------------
__global__ __launch_bounds__(256)
void prep_kernel(const float* __restrict__ s,
                 const float* __restrict__ Wq, const float* __restrict__ Wk,
                 const float* __restrict__ Wv, const float* __restrict__ Wqp,
                 const float* __restrict__ Wkp, const float* __restrict__ Wvp,
                 const float* __restrict__ Wo,
                 f16* __restrict__ sH, f16* __restrict__ WallT, f16* __restrict__ WoT)
{
    const int blk = blockIdx.x;
    const int t = threadIdx.x;
    __shared__ float tile[32][33];

    if (blk < 1024) {
        const int i = blk * 256 + t;
        float4 v = ((const float4*)s)[i];
        f16x4v o = { (f16)v.x, (f16)v.y, (f16)v.z, (f16)v.w };
        ((f16x4v*)sH)[i] = o;
        return;
    }
    if (blk < 1936) {
        const int idx = blk - 1024;
        const int n0 = (idx % 57) * 32, k0 = (idx / 57) * 32;
        const float* src; int ld, nc0;
        if      (n0 < 512)  { src = Wq;  ld = 512; nc0 = n0; }
        else if (n0 < 1024) { src = Wk;  ld = 512; nc0 = n0 - 512; }
        else if (n0 < 1536) { src = Wv;  ld = 512; nc0 = n0 - 1024; }
        else if (n0 < 1632) { src = Wqp; ld = 96;  nc0 = n0 - 1536; }
        else if (n0 < 1728) { src = Wkp; ld = 96;  nc0 = n0 - 1632; }
        else                { src = Wvp; ld = 96;  nc0 = n0 - 1728; }
#pragma unroll
        for (int i = 0; i < 4; ++i) {
            const int idx2 = t + i * 256;
            const int kl = idx2 >> 5, nl = idx2 & 31;
            tile[kl][nl] = src[(long long)(k0 + kl) * ld + nc0 + nl];
        }
        __syncthreads();
#pragma unroll
        for (int i = 0; i < 4; ++i) {
            const int idx2 = t + i * 256;
            const int nl = idx2 >> 5, kl = idx2 & 31;
            WallT[(long long)(n0 + nl) * 512 + k0 + kl] = (f16)tile[kl][nl];
        }
        return;
    }
    {
        const int idx = blk - 1936;
        const int n0 = (idx % 16) * 32, k0 = (idx / 16) * 32;
#pragma unroll
        for (int i = 0; i < 4; ++i) {
            const int idx2 = t + i * 256;
            const int kl = idx2 >> 5, nl = idx2 & 31;
            tile[kl][nl] = Wo[(long long)(k0 + kl) * 512 + n0 + nl];
        }
        __syncthreads();
#pragma unroll
        for (int i = 0; i < 4; ++i) {
            const int idx2 = t + i * 256;
            const int nl = idx2 >> 5, kl = idx2 & 31;
            WoT[(long long)(n0 + nl) * 608 + k0 + kl] = (f16)tile[kl][nl];
        }
    }
}

// ---------------------------------------------------------------------------
// Double-buffered MFMA f16 GEMM.  C[M][ldc] = A[M][K] @ Bt[N][K]^T.
// Tile 64 x BN, BK=32, 4 waves each 16 rows.
// ---------------------------------------------------------------------------
template<int BN, bool OUT16>
__global__ __launch_bounds__(256)
void gemm2_kernel(const f16* __restrict__ A, const f16* __restrict__ Bt,
                  void* __restrict__ Cout, int K, int ldc)
{
    constexpr int BCH = (BN * 4 + 255) / 256;
    __shared__ f16 As[2][64][40];
    __shared__ f16 Bs[2][BN][40];
    const int t = threadIdx.x;
    const int w = t >> 6, lane = t & 63, l15 = lane & 15, lhi = lane >> 4;
    const int row0 = blockIdx.y * 64, col0 = blockIdx.x * BN;
    const int ar = t >> 2, ac = t & 3;

    f32x4 acc[BN / 16];
#pragma unroll
    for (int n = 0; n < BN / 16; ++n) acc[n] = (f32x4){0.f, 0.f, 0.f, 0.f};

    const int nsteps = K >> 5;

    f16x8 aR;
    f16x8 bR[BCH];
    aR = *(const f16x8*)&A[(long long)(row0 + ar) * K + ac * 8];
#pragma unroll
    for (int i = 0; i < BCH; ++i) {
        const int cid = t + i * 256;
        if (cid < BN * 4) {
            const int br = cid >> 2, bc = cid & 3;
            bR[i] = *(const f16x8*)&Bt[(long long)(col0 + br) * K + bc * 8];
        }
    }
    *(f16x8*)&As[0][ar][ac * 8] = aR;
#pragma unroll
    for (int i = 0; i < BCH; ++i) {
        const int cid = t + i * 256;
        if (cid < BN * 4) *(f16x8*)&Bs[0][cid >> 2][(cid & 3) * 8] = bR[i];
    }
    __syncthreads();

    for (int st = 0; st < nsteps; ++st) {
        const int cur = st & 1;
        if (st + 1 < nsteps) {
            const int k0 = (st + 1) << 5;
            aR = *(const f16x8*)&A[(long long)(row0 + ar) * K + k0 + ac * 8];
#pragma unroll
            for (int i = 0; i < BCH; ++i) {
                const int cid = t + i * 256;
                if (cid < BN * 4) {
                    const int br = cid >> 2, bc = cid & 3;
                    bR[i] = *(const f16x8*)&Bt[(long long)(col0 + br) * K + k0 + bc * 8];
                }
            }
        }
        f16x8 af = *(const f16x8*)&As[cur][w * 16 + l15][lhi * 8];
        f16x8 bf[BN / 16];
#pragma unroll
        for (int n = 0; n < BN / 16; ++n)
            bf[n] = *(const f16x8*)&Bs[cur][n * 16 + l15][lhi * 8];
#pragma unroll
        for (int n = 0; n < BN / 16; ++n)
            acc[n] = __builtin_amdgcn_mfma_f32_16x16x32_f16(af, bf[n], acc[n], 0, 0, 0);
        if (st + 1 < nsteps) {
            *(f16x8*)&As[cur ^ 1][ar][ac * 8] = aR;
#pragma unroll
            for (int i = 0; i < BCH; ++i) {
                const int cid = t + i * 256;
                if (cid < BN * 4) *(f16x8*)&Bs[cur ^ 1][cid >> 2][(cid & 3) * 8] = bR[i];
            }
        }
        __syncthreads();
    }

    const int row = row0 + w * 16 + lhi * 4;
#pragma unroll
    for (int n = 0; n < BN / 16; ++n) {
        const int col = col0 + n * 16 + l15;
#pragma unroll
        for (int r = 0; r < 4; ++r) {
            if (OUT16) ((f16*)Cout)[(long long)(row + r) * ldc + col] = (f16)acc[n][r];
            else       ((float*)Cout)[(long long)(row + r) * ldc + col] = acc[n][r];
        }
    }
}

// ---------------------------------------------------------------------------
// Fused augment+transpose. Grid (16 l-tiles of 64, 16 bh). Produces
// QA/KA f16 [bh][1024][96], VCT f16 [bh][96][1024], KOFF f32 [bh][1024].
// ---------------------------------------------------------------------------
__global__ __launch_bounds__(256)
void build_aug2_kernel(const f16* __restrict__ P, const float* __restrict__ Rm,
                       const float* __restrict__ tr, const float* __restrict__ wC,
                       f16* __restrict__ QA, f16* __restrict__ KA,
                       f16* __restrict__ VCT, float* __restrict__ KOFF)
{
    const int l0 = blockIdx.x * 64;
    const int bh = blockIdx.y;
    const int b = bh >> 3, h = bh & 7;
    const int t = threadIdx.x;

    __shared__ float Rl[64][9];
    __shared__ float trl[64][3];
    __shared__ f16 gq[64][12];
    __shared__ f16 gk[64][12];
    __shared__ float k2[64][4];
    __shared__ f16 Vt[96][72];
    __shared__ float wcs;

    const long long blbase = (long long)b * LSEQ + l0;

    for (int i = t; i < 64 * 9; i += 256) Rl[i / 9][i % 9] = Rm[blbase * 9 + i];
    for (int i = t; i < 64 * 3; i += 256) trl[i / 3][i % 3] = tr[blbase * 3 + i];
    if (t == 0) { float x = wC[h]; wcs = log1pf(expf(x)); }
    __syncthreads();
    const float wc = wcs;

    // phase 1a: point transforms, tasks (l, proj, p) = 64*3*4
    for (int i = t; i < 768; i += 256) {
        const int l = i / 12, pp = i - l * 12;
        const int proj = pp >> 2, p = pp & 3;
        const f16* src = P + (blbase + l) * PDIM + 1536 + proj * 96 + h * 12 + p * 3;
        const float x = (float)src[0], y = (float)src[1], z = (float)src[2];
        const float gx = Rl[l][0]*x + Rl[l][1]*y + Rl[l][2]*z + trl[l][0];
        const float gy = Rl[l][3]*x + Rl[l][4]*y + Rl[l][5]*z + trl[l][1];
        const float gz = Rl[l][6]*x + Rl[l][7]*y + Rl[l][8]*z + trl[l][2];
        if (proj == 0) {
            gq[l][p * 3 + 0] = (f16)(wc * gx);
            gq[l][p * 3 + 1] = (f16)(wc * gy);
            gq[l][p * 3 + 2] = (f16)(wc * gz);
        } else if (proj == 1) {
            gk[l][p * 3 + 0] = (f16)gx;
            gk[l][p * 3 + 1] = (f16)gy;
            gk[l][p * 3 + 2] = (f16)gz;
            k2[l][p] = gx * gx + gy * gy + gz * gz;
        } else {
            Vt[64 + p * 3 + 0][l] = (f16)gx;
            Vt[64 + p * 3 + 1][l] = (f16)gy;
            Vt[64 + p * 3 + 2][l] = (f16)gz;
        }
    }
    // phase 1b: V main channels -> Vt rows 0..63 (transposed)
    for (int i = t; i < 512; i += 256) {
        const int l = i >> 3, ch = i & 7;
        f16x8 v = *(const f16x8*)&P[(blbase + l) * PDIM + 1024 + h * 64 + ch * 8];
#pragma unroll
        for (int j = 0; j < 8; ++j) Vt[ch * 8 + j][l] = v[j];
    }
    // phase 1c: zero pad rows 76..95
    for (int i = t; i < 180; i += 256) {
        const int r = 76 + i / 9, ch = i % 9;
        *(f16x8*)&Vt[r][ch * 8] = (f16x8){0,0,0,0,0,0,0,0};
    }
    __syncthreads();

    if (t < 64)
        KOFF[(long long)bh * LSEQ + l0 + t] =
            0.5f * wc * (k2[t][0] + k2[t][1] + k2[t][2] + k2[t][3]);

    // phase 2a: QA/KA rows
    for (int i = t; i < 768; i += 256) {
        const int l = i / 12, ch = i - l * 12;
        const long long prow = (blbase + l) * PDIM;
        const long long orow = ((long long)bh * LSEQ + l0 + l) * AW;
        f16x8 q, k;
        if (ch < 8) {
            f16x8 qv = *(const f16x8*)&P[prow + h * 64 + ch * 8];
            f16x8 kv = *(const f16x8*)&P[prow + 512 + h * 64 + ch * 8];
            q = qv * (f16)0.125f;
            k = kv;
        } else if (ch == 8) {
#pragma unroll
            for (int j = 0; j < 8; ++j) { q[j] = gq[l][j]; k[j] = gk[l][j]; }
        } else if (ch == 9) {
#pragma unroll
            for (int j = 0; j < 8; ++j) {
                q[j] = (j < 4) ? gq[l][8 + j] : (f16)0.f;
                k[j] = (j < 4) ? gk[l][8 + j] : (f16)0.f;
            }
        } else {
            q = (f16x8){0,0,0,0,0,0,0,0};
            k = (f16x8){0,0,0,0,0,0,0,0};
        }
        *(f16x8*)&QA[orow + ch * 8] = q;
        *(f16x8*)&KA[orow + ch * 8] = k;
    }
    // phase 2b: VCT rows (96 c x 64 l)
    for (int i = t; i < 768; i += 256) {
        const int c = i >> 3, lg = i & 7;
        *(f16x8*)&VCT[((long long)bh * AW + c) * LSEQ + l0 + lg * 8] =
            *(const f16x8*)&Vt[c][lg * 8];
    }
}

// ---------------------------------------------------------------------------
// Fused flash attention, split-KV, register-prefetch double buffer.
// Grid (16 q-tiles, 16 bh, NSPLIT). 4 waves, each 16 Q-rows. KVBLK=128.
// ---------------------------------------------------------------------------
__global__ __launch_bounds__(256, 2)
void attn_kernel(const f16* __restrict__ QA, const f16* __restrict__ KA,
                 const f16* __restrict__ VCT, const float* __restrict__ KOFF,
                 f16* __restrict__ OCp, float2* __restrict__ ML)
{
    const int bh = blockIdx.y;
    const int q0 = blockIdx.x * 64;
    const int z  = blockIdx.z;
    const int t = threadIdx.x;
    const int w = t >> 6, lane = t & 63, l15 = lane & 15, lhi = lane >> 4;

    __shared__ f16 Ks[128][104];
    __shared__ f16 Vs[96][136];
    __shared__ f16 Ps[64][136];

    const f16* qbase = QA + ((long long)bh * LSEQ + q0 + w * 16 + l15) * AW;
    f16x8 qf[3];
#pragma unroll
    for (int ks = 0; ks < 3; ++ks)
        qf[ks] = *(const f16x8*)(qbase + ks * 32 + lhi * 8);

    f32x4 Oacc[6];
#pragma unroll
    for (int nv = 0; nv < 6; ++nv) Oacc[nv] = (f32x4){0.f, 0.f, 0.f, 0.f};
    float M[4], L[4];
#pragma unroll
    for (int r = 0; r < 4; ++r) { M[r] = -1e30f; L[r] = 0.f; }

    const f16* kgbase = KA + (long long)bh * LSEQ * AW;
    const f16* vgbase = VCT + (long long)bh * AW * LSEQ;
    const float* koffb = KOFF + (long long)bh * LSEQ;

    const int kvbeg = z * (LSEQ / NSPLIT);
    const int kvend = kvbeg + LSEQ / NSPLIT;

    // prologue: stage first tile
#pragma unroll
    for (int i = 0; i < 6; ++i) {
        const int cid = t + i * 256;
        const int r = cid / 12, c = cid - r * 12;
        *(f16x8*)&Ks[r][c * 8] = *(const f16x8*)(kgbase + (long long)(kvbeg + r) * AW + c * 8);
    }
#pragma unroll
    for (int i = 0; i < 6; ++i) {
        const int cid = t + i * 256;
        const int r = cid >> 4, c = cid & 15;
        *(f16x8*)&Vs[r][c * 8] = *(const f16x8*)(vgbase + (long long)r * LSEQ + kvbeg + c * 8);
    }
    __syncthreads();

    for (int kv0 = kvbeg; kv0 < kvend; kv0 += 128) {
        const bool more = (kv0 + 128 < kvend);
        f16x8 kpre[6], vpre[6];
        if (more) {
#pragma unroll
            for (int i = 0; i < 6; ++i) {
                const int cid = t + i * 256;
                const int r = cid / 12, c = cid - r * 12;
                kpre[i] = *(const f16x8*)(kgbase + (long long)(kv0 + 128 + r) * AW + c * 8);
            }
#pragma unroll
            for (int i = 0; i < 6; ++i) {
                const int cid = t + i * 256;
                const int r = cid >> 4, c = cid & 15;
                vpre[i] = *(const f16x8*)(vgbase + (long long)r * LSEQ + kv0 + 128 + c * 8);
            }
        }

        // S = QA @ K^T : 8 col-frags x 3 k-frags
        f32x4 sc[8];
#pragma unroll
        for (int n = 0; n < 8; ++n) sc[n] = (f32x4){0.f, 0.f, 0.f, 0.f};
        __builtin_amdgcn_s_setprio(1);
#pragma unroll
        for (int n = 0; n < 8; ++n)
#pragma unroll
            for (int ks = 0; ks < 3; ++ks) {
                f16x8 kb = *(const f16x8*)&Ks[n * 16 + l15][ks * 32 + lhi * 8];
                sc[n] = __builtin_amdgcn_mfma_f32_16x16x32_f16(qf[ks], kb, sc[n], 0, 0, 0);
            }
        __builtin_amdgcn_s_setprio(0);
#pragma unroll
        for (int n = 0; n < 8; ++n) {
            const float ko = koffb[kv0 + n * 16 + l15];
#pragma unroll
            for (int r = 0; r < 4; ++r) sc[n][r] -= ko;
        }
        // online softmax
        float sscale[4];
#pragma unroll
        for (int r = 0; r < 4; ++r) {
            float mr = sc[0][r];
#pragma unroll
            for (int n = 1; n < 8; ++n) mr = fmaxf(mr, sc[n][r]);
#pragma unroll
            for (int off = 1; off < 16; off <<= 1) mr = fmaxf(mr, __shfl_xor(mr, off));
            const float nm = fmaxf(M[r], mr);
            sscale[r] = __expf(M[r] - nm);
            M[r] = nm;
        }
        float rsum[4] = {0.f, 0.f, 0.f, 0.f};
#pragma unroll
        for (int n = 0; n < 8; ++n)
#pragma unroll
            for (int r = 0; r < 4; ++r) {
                const float p = __expf(sc[n][r] - M[r]);
                sc[n][r] = p;
                rsum[r] += p;
            }
#pragma unroll
        for (int r = 0; r < 4; ++r) {
            float s = rsum[r];
#pragma unroll
            for (int off = 1; off < 16; off <<= 1) s += __shfl_xor(s, off);
            L[r] = L[r] * sscale[r] + s;
        }
#pragma unroll
        for (int nv = 0; nv < 6; ++nv)
#pragma unroll
            for (int r = 0; r < 4; ++r) Oacc[nv][r] *= sscale[r];

        // P -> LDS (own wave's rows; in-wave DS ordering guarantees RAW)
#pragma unroll
        for (int n = 0; n < 8; ++n)
#pragma unroll
            for (int r = 0; r < 4; ++r)
                Ps[w * 16 + lhi * 4 + r][n * 16 + l15] = (f16)sc[n][r];

        f16x8 pa[4];
#pragma unroll
        for (int ks = 0; ks < 4; ++ks)
            pa[ks] = *(const f16x8*)&Ps[w * 16 + l15][ks * 32 + lhi * 8];
        __builtin_amdgcn_s_setprio(1);
#pragma unroll
        for (int nv = 0; nv < 6; ++nv)
#pragma unroll
            for (int ks = 0; ks < 4; ++ks) {
                f16x8 vb = *(const f16x8*)&Vs[nv * 16 + l15][ks * 32 + lhi * 8];
                Oacc[nv] = __builtin_amdgcn_mfma_f32_16x16x32_f16(pa[ks], vb, Oacc[nv], 0, 0, 0);
            }
        __builtin_amdgcn_s_setprio(0);
        __syncthreads();

        if (more) {
#pragma unroll
            for (int i = 0; i < 6; ++i) {
                const int cid = t + i * 256;
                const int r = cid / 12, c = cid - r * 12;
                *(f16x8*)&Ks[r][c * 8] = kpre[i];
            }
#pragma unroll
            for (int i = 0; i < 6; ++i) {
                const int cid = t + i * 256;
                const int r = cid >> 4, c = cid & 15;
                *(f16x8*)&Vs[r][c * 8] = vpre[i];
            }
        }
        __syncthreads();
    }

    f16* obase = OCp + (((long long)(z * 16 + bh) * LSEQ) + q0 + w * 16 + lhi * 4) * AW;
#pragma unroll
    for (int nv = 0; nv < 6; ++nv)
#pragma unroll
        for (int r = 0; r < 4; ++r)
            obase[r * AW + nv * 16 + l15] = (f16)Oacc[nv][r];
    if (l15 == 0) {
#pragma unroll
        for (int r = 0; r < 4; ++r)
            ML[(long long)(z * 16 + bh) * LSEQ + q0 + w * 16 + lhi * 4 + r] =
                make_float2(M[r], L[r]);
    }
}

// ---------------------------------------------------------------------------
// Combine splits (LSE merge) + un-rotate + concat -> CC f16 [2048][608]
// ---------------------------------------------------------------------------
__global__ __launch_bounds__(256)
void combine_concat_kernel(const f16* __restrict__ OCp, const float2* __restrict__ ML,
                           const float* __restrict__ Rm, const float* __restrict__ tr,
                           f16* __restrict__ CC)
{
    const int bl = blockIdx.x;
    const int b = bl >> 10, l = bl & 1023;
    const int t = threadIdx.x;

    __shared__ float w1[8], w2[8];
    __shared__ float o[8][AW];
    __shared__ float Rloc[9], trloc[3];
    if (t < 9) Rloc[t] = Rm[(long long)bl * 9 + t];
    if (t < 3) trloc[t] = tr[(long long)bl * 3 + t];
    if (t < 8) {
        const int bh = b * 8 + t;
        const float2 m1 = ML[(long long)bh * LSEQ + l];
        const float2 m2 = ML[(long long)(16 + bh) * LSEQ + l];
        const float mm = fmaxf(m1.x, m2.x);
        const float e1 = __expf(m1.x - mm), e2 = __expf(m2.x - mm);
        const float inv = 1.0f / (m1.y * e1 + m2.y * e2);
        w1[t] = e1 * inv; w2[t] = e2 * inv;
    }
    __syncthreads();
    for (int idx = t; idx < 8 * AW; idx += 256) {
        const int h = idx / AW, c = idx - h * AW;
        const f16* p1 = OCp + ((long long)(b * 8 + h) * LSEQ + l) * AW;
        const f16* p2 = OCp + ((long long)(16 + b * 8 + h) * LSEQ + l) * AW;
        o[h][c] = (float)p1[c] * w1[h] + (float)p2[c] * w2[h];
    }
    __syncthreads();

    f16* crow = CC + (long long)bl * ODIM;
    for (int c = t; c < DMODEL; c += 256) crow[c] = (f16)o[c >> 6][c & 63];
    if (t < 32) {
        const int h = t >> 2, p = t & 3;
        const float x = o[h][64 + p * 3 + 0] - trloc[0];
        const float y = o[h][64 + p * 3 + 1] - trloc[1];
        const float z = o[h][64 + p * 3 + 2] - trloc[2];
        crow[512 + h * 12 + p * 3 + 0] = (f16)(Rloc[0]*x + Rloc[3]*y + Rloc[6]*z);
        crow[512 + h * 12 + p * 3 + 1] = (f16)(Rloc[1]*x + Rloc[4]*y + Rloc[7]*z);
        crow[512 + h * 12 + p * 3 + 2] = (f16)(Rloc[2]*x + Rloc[5]*y + Rloc[8]*z);
    }
}

// ---------------------------------------------------------------------------
// out = LayerNorm(s + Y + bo) * gamma + beta
// ---------------------------------------------------------------------------
__global__ __launch_bounds__(256)
void residual_ln_kernel(const float* __restrict__ s, const float* __restrict__ Y,
                        const float* __restrict__ bo, const float* __restrict__ gamma,
                        const float* __restrict__ beta, float* __restrict__ out)
{
    const int bl = blockIdx.x;
    const int t = threadIdx.x;
    const float* srow = s + (long long)bl * DMODEL;
    const float* yrow = Y + (long long)bl * DMODEL;

    const float v0 = srow[t]       + yrow[t]       + bo[t];
    const float v1 = srow[t + 256] + yrow[t + 256] + bo[t + 256];

    float sum = v0 + v1, sq = v0 * v0 + v1 * v1;
#pragma unroll
    for (int o = 32; o > 0; o >>= 1) {
        sum += __shfl_xor(sum, o);
        sq  += __shfl_xor(sq,  o);
    }
    __shared__ float rs[4], rq[4];
    const int wid = t >> 6, lane = t & 63;
    if (lane == 0) { rs[wid] = sum; rq[wid] = sq; }
    __syncthreads();
    sum = rs[0] + rs[1] + rs[2] + rs[3];
    sq  = rq[0] + rq[1] + rq[2] + rq[3];

    const float mu  = sum * (1.0f / DMODEL);
    const float var = sq * (1.0f / DMODEL) - mu * mu;
    const float inv = rsqrtf(var + 1e-5f);

    out[(long long)bl * DMODEL + t]       = (v0 - mu) * inv * gamma[t]       + beta[t];
    out[(long long)bl * DMODEL + t + 256] = (v1 - mu) * inv * gamma[t + 256] + beta[t + 256];
}

// ---------------------------------------------------------------------------
extern "C" void kernel_launch(void* const* d_in, const int* in_sizes, int n_in,
                              void* d_out, int out_size, void* d_ws, size_t ws_size,
                              hipStream_t stream)
{
    const float* s    = (const float*)d_in[0];
    const float* R    = (const float*)d_in[1];
    const float* tr   = (const float*)d_in[2];
    const float* Wq   = (const float*)d_in[3];
    const float* Wk   = (const float*)d_in[4];
    const float* Wv   = (const float*)d_in[5];
    const float* Wqp  = (const float*)d_in[6];
    const float* Wkp  = (const float*)d_in[7];
    const float* Wvp  = (const float*)d_in[8];
    const float* Wo   = (const float*)d_in[9];
    const float* bo   = (const float*)d_in[10];
    const float* gam  = (const float*)d_in[11];
    const float* bet  = (const float*)d_in[12];
    const float* wC   = (const float*)d_in[13];
    float* out = (float*)d_out;

    // workspace layout
    f16* sH    = (f16*)d_ws;                       // 1,048,576
    f16* WallT = sH + 1048576;                     // 933,888
    f16* WoT   = WallT + 933888;                   // 311,296
    f16* P     = WoT + 311296;                     // 3,735,552
    f16* QA    = P + 3735552;                      // 1,572,864
    f16* KA    = QA + 1572864;
    f16* VCT   = KA + 1572864;
    float* KOFF = (float*)(VCT + 1572864);         // 16,384 f32
    f16* OCp    = (f16*)(KOFF + 16384);            // 3,145,728 f16 (2 splits)
    float2* ML  = (float2*)(OCp + 3145728);        // 32,768 float2
    f16* CC     = (f16*)(ML + 32768);              // 1,245,184
    float* Y    = (float*)(CC + 1245184);          // 1,048,576 f32

    const dim3 blk(256);

    prep_kernel<<<dim3(2240), blk, 0, stream>>>(s, Wq, Wk, Wv, Wqp, Wkp, Wvp, Wo,
                                                sH, WallT, WoT);

    // projections: P = sH @ WallT^T   (M=2048, N=1824, K=512)
    gemm2_kernel<96, true><<<dim3(19, 32), blk, 0, stream>>>(sH, WallT, P, 512, 1824);

    build_aug2_kernel<<<dim3(16, 16), blk, 0, stream>>>(P, R, tr, wC, QA, KA, VCT, KOFF);

    attn_kernel<<<dim3(16, 16, NSPLIT), blk, 0, stream>>>(QA, KA, VCT, KOFF, OCp, ML);

    combine_concat_kernel<<<dim3(BLTOT), blk, 0, stream>>>(OCp, ML, R, tr, CC);

    // output projection: Y = CC @ WoT^T  (M=2048, N=512, K=608)
    gemm2_kernel<64, false><<<dim3(8, 32), blk, 0, stream>>>(CC, WoT, Y, 608, 512);

    residual_ln_kernel<<<dim3(BLTOT), blk, 0, stream>>>(s, Y, bo, gam, bet, out);
}